// Round 5
// baseline (629.227 us; speedup 1.0000x reference)
//
#include <hip/hip_runtime.h>

// GSModel pipeline, round 5.
//  - p_b = sum(g1_b) - sum(g2_b) identity (sinkhorn colsum==1) — scores path removed.
//  - bf16 storage; fused GIN layer GEMMs (MFMA 16x16x32 bf16, swizzled LDS).
//  - k_agg v3: COLUMN-CHUNKED gather for L2 residency. 4 chunks x 64 cols:
//    per-(side,chunk) gather working set = 4MB = one XCD L2. Chunk-major block
//    order clusters co-resident blocks on the same working set; nontemporal
//    output stores avoid evicting it. Half-wave per node, uint (2xbf16) lanes,
//    edge loop unrolled x4.

constexpr int NNODE = 32768;
constexpr int NEDGE = 524288;

typedef __attribute__((ext_vector_type(8))) short bf16x8;
typedef __attribute__((ext_vector_type(4))) float f32x4;

__device__ __forceinline__ float bf2f(unsigned short u) {
  return __uint_as_float((unsigned)u << 16);
}
__device__ __forceinline__ unsigned short f2bf(float f) {
  unsigned u = __float_as_uint(f);
  return (unsigned short)((u + 0x7FFFu + ((u >> 16) & 1u)) >> 16);
}
__device__ __forceinline__ unsigned packbf(float a, float b) {
  return (unsigned)f2bf(a) | ((unsigned)f2bf(b) << 16);
}

// ---------------- feature convert f32 -> bf16 ----------------
__global__ __launch_bounds__(256) void k_conv(const float* __restrict__ a,
                                              const float* __restrict__ b,
                                              unsigned short* __restrict__ out) {
  size_t i = (size_t)blockIdx.x * 256 + threadIdx.x;   // 4,194,304 chunks of 4
  const float* src = (i < 2097152) ? (a + i * 4) : (b + (i - 2097152) * 4);
  float4 v = *(const float4*)src;
  ushort4 o;
  o.x = f2bf(v.x); o.y = f2bf(v.y); o.z = f2bf(v.z); o.w = f2bf(v.w);
  *(ushort4*)(out + i * 4) = o;
}

// ---------------- weight transpose + convert: Wt[n][k] = W[k][n], bf16 ----------------
__global__ __launch_bounds__(256) void k_wprep(const float* __restrict__ gw1,
                                               const float* __restrict__ gw2,
                                               unsigned short* __restrict__ Wt) {
  __shared__ float sh[64][65];
  int b = blockIdx.x;            // 96 = 6 mats x 16 tiles of 64x64
  int mat = b >> 4, tile = b & 15;
  int tr = (tile >> 2) * 64, tc = (tile & 3) * 64;
  const float* src = (mat < 3) ? (gw1 + (size_t)mat * 65536) : (gw2 + (size_t)(mat - 3) * 65536);
  int t = threadIdx.x;
#pragma unroll
  for (int i = 0; i < 4; i++) {
    int c = t + i * 256;         // 1024 float4 chunks
    int row = c >> 4, c4 = (c & 15) * 4;
    float4 v = *(const float4*)(src + (size_t)(tr + row) * 256 + tc + c4);
    sh[row][c4] = v.x; sh[row][c4 + 1] = v.y; sh[row][c4 + 2] = v.z; sh[row][c4 + 3] = v.w;
  }
  __syncthreads();
#pragma unroll
  for (int i = 0; i < 2; i++) {
    int c = t + i * 256;         // 512 chunks of 8 bf16
    int n = c >> 3, kc = (c & 7) * 8;
    unsigned short e[8];
#pragma unroll
    for (int j = 0; j < 8; j++) e[j] = f2bf(sh[kc + j][n]);
    uint4 o;
    o.x = e[0] | ((unsigned)e[1] << 16);
    o.y = e[2] | ((unsigned)e[3] << 16);
    o.z = e[4] | ((unsigned)e[5] << 16);
    o.w = e[6] | ((unsigned)e[7] << 16);
    *(uint4*)(Wt + (size_t)mat * 65536 + (size_t)(tc + n) * 256 + tr + kc) = o;
  }
}

// ---------------- CSR build (both sides per launch) ----------------
__global__ void k_degree2(const int* __restrict__ e1, const int* __restrict__ e2,
                          int* __restrict__ cnt) {
  int b = blockIdx.x;                 // 4096
  int side = b >> 11;
  int e = (b & 2047) * 256 + threadIdx.x;
  const int* dst = (side ? e2 : e1) + NEDGE;
  atomicAdd(&cnt[side * NNODE + dst[e]], 1);
}

__global__ void k_scan2(const int* __restrict__ cnt, int* __restrict__ off,
                        int* __restrict__ cur) {
  __shared__ int sh[1024];
  int side = blockIdx.x;              // grid 2
  const int* c = cnt + side * NNODE;
  int* of = off + side * (NNODE + 64);
  int* cu = cur + side * NNODE;
  int t = threadIdx.x;
  int base = t * 32;
  int loc[32];
  int s = 0;
#pragma unroll
  for (int j = 0; j < 32; j++) { loc[j] = c[base + j]; s += loc[j]; }
  sh[t] = s;
  __syncthreads();
  for (int d = 1; d < 1024; d <<= 1) {
    int v = (t >= d) ? sh[t - d] : 0;
    __syncthreads();
    sh[t] += v;
    __syncthreads();
  }
  int run = sh[t] - s;
#pragma unroll
  for (int j = 0; j < 32; j++) { of[base + j] = run; cu[base + j] = run; run += loc[j]; }
  if (t == 1023) of[NNODE] = run;
}

__global__ void k_scatter2(const int* __restrict__ e1, const int* __restrict__ e2,
                           int* __restrict__ cur, int* __restrict__ srcs) {
  int b = blockIdx.x;                 // 4096
  int side = b >> 11;
  int e = (b & 2047) * 256 + threadIdx.x;
  const int* ei = (side ? e2 : e1);
  int d = ei[NEDGE + e];
  int p = atomicAdd(&cur[side * NNODE + d], 1);
  srcs[side * NEDGE + p] = ei[e];
}

// ---------------- aggregate: out = 2*x' + segsum(x'), x' = (BN? relu(bn(h)) : h) ----------------
// Column-chunked: grid = [chunk(4)][side(2)][nb(4096)], 256 thr, half-wave per node,
// lane = 4B (2 bf16 cols). Per-(chunk,side) gather WS = 4MB -> XCD L2 resident.
template <bool BN>
__global__ __launch_bounds__(256) void k_agg(
    const unsigned short* __restrict__ x,    // [2*NNODE][256] bf16
    const int* __restrict__ off, const int* __restrict__ srcs,
    const float* __restrict__ stats,         // [2][2][256] prev layer (BN only)
    const float* __restrict__ gamma, const float* __restrict__ beta,
    unsigned short* __restrict__ out) {
  int b = blockIdx.x;
  int nb = b & 4095, side = (b >> 12) & 1, chunk = b >> 13;
  int tid = threadIdx.x;
  int lane = tid & 63;
  int half = lane >> 5, sub = lane & 31;
  int n = nb * 8 + (tid >> 6) * 2 + half;          // node within side, 0..32767

  float sc0 = 1.f, sc1 = 1.f, sh0 = 0.f, sh1 = 0.f;
  int col = chunk * 64 + sub * 2;
  if (BN) {
    const float* cs = stats + side * 512;
    const float invn = 1.f / 32768.f;
    float mu0 = cs[col] * invn, mu1 = cs[col + 1] * invn;
    float v0 = cs[256 + col] * invn - mu0 * mu0;
    float v1 = cs[256 + col + 1] * invn - mu1 * mu1;
    sc0 = gamma[col] * rsqrtf(v0 + 1e-5f);
    sc1 = gamma[col + 1] * rsqrtf(v1 + 1e-5f);
    sh0 = beta[col] - mu0 * sc0;
    sh1 = beta[col + 1] - mu1 * sc1;
  }

  const unsigned* X = (const unsigned*)x;          // row stride 128 uints
  size_t rbase = (size_t)side * NNODE;
  int cb = chunk * 32 + sub;

  float a0 = 0.f, a1 = 0.f;
#define ACC(u, w) do { \
    float lo = __uint_as_float((u) << 16); \
    float hi = __uint_as_float((u) & 0xFFFF0000u); \
    if (BN) { \
      lo = fmaxf(fmaf(lo, sc0, sh0), 0.f); \
      hi = fmaxf(fmaf(hi, sc1, sh1), 0.f); \
    } \
    a0 = fmaf(lo, (w), a0); a1 = fmaf(hi, (w), a1); \
  } while (0)

  // self * 2
  {
    unsigned u = X[(rbase + n) * 128 + cb];
    ACC(u, 2.f);
  }
  const int* offs = off + side * (NNODE + 64);
  const int* sr = srcs + (size_t)side * NEDGE;
  int e = offs[n], eend = offs[n + 1];
  for (; e + 3 < eend; e += 4) {
    int i0 = sr[e], i1 = sr[e + 1], i2 = sr[e + 2], i3 = sr[e + 3];
    unsigned u0 = X[(rbase + i0) * 128 + cb];
    unsigned u1 = X[(rbase + i1) * 128 + cb];
    unsigned u2 = X[(rbase + i2) * 128 + cb];
    unsigned u3 = X[(rbase + i3) * 128 + cb];
    ACC(u0, 1.f); ACC(u1, 1.f); ACC(u2, 1.f); ACC(u3, 1.f);
  }
  for (; e < eend; e++) {
    unsigned u = X[(rbase + sr[e]) * 128 + cb];
    ACC(u, 1.f);
  }
#undef ACC

  __builtin_nontemporal_store(packbf(a0, a1), (unsigned*)out + (rbase + n) * 128 + cb);
}

// ---------------- fused GIN layer: h = (relu(Aggr@W1+b1))@W2 + b2, + BN stats ----------------
// grid 1024 (2 sides x 512 row-blocks of 64), 512 thr = 8 waves (2m x 4n), wave tile 32x64.
// LDS 64KB: sA2 [64][512B] at [0,32K) (sA [64][128B] aliased at [0,8K)), sW [256][128B] at [32K,64K).
__global__ __launch_bounds__(512) void k_gin(
    const unsigned short* __restrict__ Aggr,   // [2*N][256] bf16
    const unsigned short* __restrict__ w1t,    // [256][256] bf16, transposed
    const unsigned short* __restrict__ w2t,
    const float* __restrict__ b1, const float* __restrict__ b2,
    float* __restrict__ stats,                 // [2][2][256] this layer
    unsigned short* __restrict__ hout) {
  __shared__ __align__(16) char smem[65536];
  char* sA2 = smem;                // 32KB
  char* sA = smem;                 // 8KB alias (phase1 only)
  char* sW = smem + 32768;         // 32KB
  int tid = threadIdx.x;
  int lane = tid & 63, wid = tid >> 6;
  int wm = wid & 1, wn = wid >> 1;
  int q = lane >> 4, r = lane & 15;
  const int sw = (r & 7) << 4;
  int b = blockIdx.x;
  int side = b >> 9;
  size_t grow0 = (size_t)side * NNODE + (size_t)(b & 511) * 64;

  auto stageA = [&](int k0) {
    int c = tid;                   // 512 chunks of 16B: 64 rows x 8
    int row = c >> 3, cb = (c & 7) * 16;
    float4 v = *(const float4*)(Aggr + (grow0 + row) * 256 + k0 + (c & 7) * 8);
    *(float4*)(sA + row * 128 + (cb ^ ((row & 7) << 4))) = v;
  };
  auto stageW = [&](const unsigned short* wsrc, int k0) {
    for (int c = tid; c < 2048; c += 512) {
      int row = c >> 3, cb = (c & 7) * 16;
      float4 v = *(const float4*)(wsrc + (size_t)row * 256 + k0 + (c & 7) * 8);
      *(float4*)(sW + row * 128 + (cb ^ ((row & 7) << 4))) = v;
    }
  };

  f32x4 acc[2][4];
#pragma unroll
  for (int mi = 0; mi < 2; mi++)
#pragma unroll
    for (int ni = 0; ni < 4; ni++) acc[mi][ni] = (f32x4){0.f, 0.f, 0.f, 0.f};

  // ---- phase 1: C1 = Aggr @ W1 ----
  for (int k0 = 0; k0 < 256; k0 += 64) {
    stageA(k0);
    stageW(w1t, k0);
    __syncthreads();
#pragma unroll
    for (int ks = 0; ks < 2; ks++) {
      bf16x8 af[2], bfr[4];
      int cb = (ks * 64 + q * 16) ^ sw;
#pragma unroll
      for (int mi = 0; mi < 2; mi++)
        af[mi] = *(const bf16x8*)(sA + (wm * 32 + mi * 16 + r) * 128 + cb);
#pragma unroll
      for (int ni = 0; ni < 4; ni++)
        bfr[ni] = *(const bf16x8*)(sW + (wn * 64 + ni * 16 + r) * 128 + cb);
#pragma unroll
      for (int mi = 0; mi < 2; mi++)
#pragma unroll
        for (int ni = 0; ni < 4; ni++)
          acc[mi][ni] = __builtin_amdgcn_mfma_f32_16x16x32_bf16(af[mi], bfr[ni], acc[mi][ni], 0, 0, 0);
    }
    __syncthreads();
  }

  // epilogue 1: bias + relu -> bf16 into sA2 (row-swizzled)
  float b1v[4];
#pragma unroll
  for (int ni = 0; ni < 4; ni++) b1v[ni] = b1[wn * 64 + ni * 16 + r];
#pragma unroll
  for (int mi = 0; mi < 2; mi++)
#pragma unroll
    for (int ni = 0; ni < 4; ni++)
#pragma unroll
      for (int j = 0; j < 4; j++) {
        float o = fmaxf(acc[mi][ni][j] + b1v[ni], 0.f);
        int rowc = wm * 32 + mi * 16 + q * 4 + j;
        int colc = wn * 64 + ni * 16 + r;
        *(unsigned short*)(sA2 + rowc * 512 + ((colc * 2) ^ (((q * 4 + j) & 7) << 4))) = f2bf(o);
      }
#pragma unroll
  for (int mi = 0; mi < 2; mi++)
#pragma unroll
    for (int ni = 0; ni < 4; ni++) acc[mi][ni] = (f32x4){0.f, 0.f, 0.f, 0.f};
  __syncthreads();

  // ---- phase 2: C2 = relu(C1) @ W2 ----
  for (int k0 = 0; k0 < 256; k0 += 64) {
    stageW(w2t, k0);
    __syncthreads();
#pragma unroll
    for (int ks = 0; ks < 2; ks++) {
      bf16x8 af[2], bfr[4];
      int cbW = (ks * 64 + q * 16) ^ sw;
#pragma unroll
      for (int mi = 0; mi < 2; mi++) {
        int cbA = (k0 * 2 + ks * 64 + q * 16) ^ sw;
        af[mi] = *(const bf16x8*)(sA2 + (wm * 32 + mi * 16 + r) * 512 + cbA);
      }
#pragma unroll
      for (int ni = 0; ni < 4; ni++)
        bfr[ni] = *(const bf16x8*)(sW + (wn * 64 + ni * 16 + r) * 128 + cbW);
#pragma unroll
      for (int mi = 0; mi < 2; mi++)
#pragma unroll
        for (int ni = 0; ni < 4; ni++)
          acc[mi][ni] = __builtin_amdgcn_mfma_f32_16x16x32_bf16(af[mi], bfr[ni], acc[mi][ni], 0, 0, 0);
    }
    __syncthreads();
  }

  // epilogue 2: bias, BN stats (shfl + LDS cross-wave reduce + atomics), bf16 out
  float b2v[4];
#pragma unroll
  for (int ni = 0; ni < 4; ni++) b2v[ni] = b2[wn * 64 + ni * 16 + r];
  float2* red = (float2*)sW;       // [256 cols][2 wm] — sW dead after phase 2
#pragma unroll
  for (int ni = 0; ni < 4; ni++) {
    float ss = 0.f, sq = 0.f;
#pragma unroll
    for (int mi = 0; mi < 2; mi++)
#pragma unroll
      for (int j = 0; j < 4; j++) {
        float o = acc[mi][ni][j] + b2v[ni];
        acc[mi][ni][j] = o;
        ss += o; sq += o * o;
      }
    ss += __shfl_xor(ss, 16, 64); ss += __shfl_xor(ss, 32, 64);
    sq += __shfl_xor(sq, 16, 64); sq += __shfl_xor(sq, 32, 64);
    if (q == 0) {
      float2 w; w.x = ss; w.y = sq;
      red[(wn * 64 + ni * 16 + r) * 2 + wm] = w;
    }
  }
#pragma unroll
  for (int mi = 0; mi < 2; mi++)
#pragma unroll
    for (int ni = 0; ni < 4; ni++)
#pragma unroll
      for (int j = 0; j < 4; j++) {
        int rowc = wm * 32 + mi * 16 + q * 4 + j;
        int colc = wn * 64 + ni * 16 + r;
        *(unsigned short*)(sA2 + rowc * 512 + ((colc * 2) ^ (((q * 4 + j) & 7) << 4))) =
            f2bf(acc[mi][ni][j]);
      }
  __syncthreads();
  float* cs = stats + side * 512;
  if (tid < 256) {
    float2 a = red[tid * 2], c2 = red[tid * 2 + 1];
    atomicAdd(&cs[tid], a.x + c2.x);
    atomicAdd(&cs[256 + tid], a.y + c2.y);
  }
  for (int c = tid; c < 2048; c += 512) {   // 64 rows x 32 chunks of 16B
    int row = c >> 5, cb = (c & 31) * 16;
    float4 v = *(const float4*)(sA2 + row * 512 + (cb ^ ((row & 7) << 4)));
    *(float4*)(hout + (grow0 + row) * 256 + (c & 31) * 8) = v;
  }
}

// ---------------- per-graph sum of relu(bn(h)) ----------------
__global__ __launch_bounds__(256) void k_gsum(
    const unsigned short* __restrict__ h, const float* __restrict__ stats,
    const float* __restrict__ gamma, const float* __restrict__ beta,
    float* __restrict__ sg) {
  int b = blockIdx.x;            // 256 = 2 sides x 128 graphs
  int side = b >> 7, g = b & 127;
  int t = threadIdx.x;
  int c0 = (t & 63) * 4, rg = t >> 6;
  const float* cs = stats + side * 512;
  float sc[4], sh_[4];
#pragma unroll
  for (int j = 0; j < 4; j++) {
    float mu = cs[c0 + j] * (1.f / 32768.f);
    float var = cs[256 + c0 + j] * (1.f / 32768.f) - mu * mu;
    float s = gamma[c0 + j] * rsqrtf(var + 1e-5f);
    sc[j] = s; sh_[j] = beta[c0 + j] - mu * s;
  }
  size_t base = (size_t)side * NNODE + (size_t)g * 256;
  float acc = 0.f;
  for (int k = 0; k < 64; k++) {
    int row = rg + k * 4;
    ushort4 u = *(const ushort4*)(h + (base + row) * 256 + c0);
    acc += fmaxf(fmaf(bf2f(u.x), sc[0], sh_[0]), 0.f);
    acc += fmaxf(fmaf(bf2f(u.y), sc[1], sh_[1]), 0.f);
    acc += fmaxf(fmaf(bf2f(u.z), sc[2], sh_[2]), 0.f);
    acc += fmaxf(fmaf(bf2f(u.w), sc[3], sh_[3]), 0.f);
  }
  __shared__ float red[256];
  red[t] = acc;
  __syncthreads();
  if (t < 64) {
    float s = red[t] + red[t + 64] + red[t + 128] + red[t + 192];
#pragma unroll
    for (int m = 1; m < 64; m <<= 1) s += __shfl_xor(s, m, 64);
    if (t == 0) sg[b] = s;
  }
}

// ---------------- final: p = sg1 - sg2, min-max normalize, exp(-p) ----------------
__global__ void k_final(const float* __restrict__ sg1, const float* __restrict__ sg2,
                        float* __restrict__ out) {
  int t = threadIdx.x;   // 64 threads
  float a = sg1[t] - sg2[t];
  float b = sg1[t + 64] - sg2[t + 64];
  float mn = fminf(a, b), mx = fmaxf(a, b);
#pragma unroll
  for (int msk = 1; msk < 64; msk <<= 1) {
    mn = fminf(mn, __shfl_xor(mn, msk, 64));
    mx = fmaxf(mx, __shfl_xor(mx, msk, 64));
  }
  float inv = 1.0f / (mx - mn);
  out[t] = __expf(-(a - mn) * inv);
  out[t + 64] = __expf(-(b - mn) * inv);
}

// ---------------- host ----------------
extern "C" void kernel_launch(void* const* d_in, const int* in_sizes, int n_in,
                              void* d_out, int out_size, void* d_ws, size_t ws_size,
                              hipStream_t stream) {
  (void)in_sizes; (void)n_in; (void)out_size; (void)ws_size;
  const float* f1 = (const float*)d_in[0];
  const float* f2 = (const float*)d_in[1];
  const int* e1 = (const int*)d_in[2];
  const int* e2 = (const int*)d_in[3];
  const float* gw1 = (const float*)d_in[5];
  const float* gb1 = (const float*)d_in[6];
  const float* gw2 = (const float*)d_in[7];
  const float* gb2 = (const float*)d_in[8];
  const float* gga = (const float*)d_in[9];
  const float* gbe = (const float*)d_in[10];
  float* out = (float*)d_out;

  char* ws = (char*)d_ws;
  size_t o = 0;
  auto alloc = [&](size_t bytes) { void* p = ws + o; o += (bytes + 255) & ~(size_t)255; return p; };
  unsigned short* hbuf = (unsigned short*)alloc(2ull * NNODE * 256 * 2);
  unsigned short* aggr = (unsigned short*)alloc(2ull * NNODE * 256 * 2);
  unsigned short* Wt = (unsigned short*)alloc(6ull * 65536 * 2);
  float* stats = (float*)alloc(3 * 1024 * 4);      // [layer][side][{sum,sq}][256]
  float* sg = (float*)alloc(256 * 4);
  int* cnt = (int*)alloc(2 * NNODE * 4);
  int* off = (int*)alloc(2 * (NNODE + 64) * 4);
  int* cur = (int*)alloc(2 * NNODE * 4);
  int* srcs = (int*)alloc(2ull * NEDGE * 4);

  hipMemsetAsync(stats, 0, 3 * 1024 * 4, stream);
  hipMemsetAsync(cnt, 0, 2 * NNODE * 4, stream);

  k_conv<<<16384, 256, 0, stream>>>(f1, f2, hbuf);
  k_wprep<<<96, 256, 0, stream>>>(gw1, gw2, Wt);
  k_degree2<<<4096, 256, 0, stream>>>(e1, e2, cnt);
  k_scan2<<<2, 1024, 0, stream>>>(cnt, off, cur);
  k_scatter2<<<4096, 256, 0, stream>>>(e1, e2, cur, srcs);

  for (int l = 0; l < 3; l++) {
    if (l == 0)
      k_agg<false><<<32768, 256, 0, stream>>>(hbuf, off, srcs, nullptr, nullptr, nullptr, aggr);
    else
      k_agg<true><<<32768, 256, 0, stream>>>(hbuf, off, srcs, stats + (l - 1) * 1024,
                                             gga + (l - 1) * 256, gbe + (l - 1) * 256, aggr);
    k_gin<<<1024, 512, 0, stream>>>(aggr, Wt + (size_t)l * 65536, Wt + (size_t)(3 + l) * 65536,
                                    gb1 + l * 256, gb2 + l * 256, stats + l * 1024, hbuf);
  }

  k_gsum<<<256, 256, 0, stream>>>(hbuf, stats + 2 * 1024, gga + 512, gbe + 512, sg);
  k_final<<<1, 64, 0, stream>>>(sg, sg + 128, out);
}

// Round 7
// 501.426 us; speedup vs baseline: 1.2549x; 1.2549x over previous
//
#include <hip/hip_runtime.h>

// GSModel pipeline, round 7 (= round 6 design, compile fix: macro -> lambda).
//  - p_b = sum(g1_b) - sum(g2_b) identity (sinkhorn colsum==1) — scores path removed.
//  - bf16 storage; MFMA 16x16x32 bf16, XOR-swizzled LDS.
//  - k_layer: FUSED gather(+prev-BN) -> LDS A-tile -> GEMM1(relu) -> GEMM2 + BN stats
//    per 64-row block. Gather (latency-bound) of one block overlaps MFMA of the
//    co-resident block (2 blocks/CU, 68KB LDS, __launch_bounds__(512,4)).
//    Kills the aggr HBM round-trip (32MB/layer) and 2 dispatches/layer.
//  - h ping-pong buffers (gather reads prev h while writing new h).

constexpr int NNODE = 32768;
constexpr int NEDGE = 524288;

typedef __attribute__((ext_vector_type(8))) short bf16x8;
typedef __attribute__((ext_vector_type(4))) float f32x4;

__device__ __forceinline__ float bf2f(unsigned short u) {
  return __uint_as_float((unsigned)u << 16);
}
__device__ __forceinline__ unsigned short f2bf(float f) {
  unsigned u = __float_as_uint(f);
  return (unsigned short)((u + 0x7FFFu + ((u >> 16) & 1u)) >> 16);
}
__device__ __forceinline__ unsigned packbf(float a, float b) {
  return (unsigned)f2bf(a) | ((unsigned)f2bf(b) << 16);
}

// ---------------- feature convert f32 -> bf16 ----------------
__global__ __launch_bounds__(256) void k_conv(const float* __restrict__ a,
                                              const float* __restrict__ b,
                                              unsigned short* __restrict__ out) {
  size_t i = (size_t)blockIdx.x * 256 + threadIdx.x;   // 4,194,304 chunks of 4
  const float* src = (i < 2097152) ? (a + i * 4) : (b + (i - 2097152) * 4);
  float4 v = *(const float4*)src;
  ushort4 o;
  o.x = f2bf(v.x); o.y = f2bf(v.y); o.z = f2bf(v.z); o.w = f2bf(v.w);
  *(ushort4*)(out + i * 4) = o;
}

// ---------------- weight transpose + convert: Wt[n][k] = W[k][n], bf16 ----------------
__global__ __launch_bounds__(256) void k_wprep(const float* __restrict__ gw1,
                                               const float* __restrict__ gw2,
                                               unsigned short* __restrict__ Wt) {
  __shared__ float sh[64][65];
  int b = blockIdx.x;            // 96 = 6 mats x 16 tiles of 64x64
  int mat = b >> 4, tile = b & 15;
  int tr = (tile >> 2) * 64, tc = (tile & 3) * 64;
  const float* src = (mat < 3) ? (gw1 + (size_t)mat * 65536) : (gw2 + (size_t)(mat - 3) * 65536);
  int t = threadIdx.x;
#pragma unroll
  for (int i = 0; i < 4; i++) {
    int c = t + i * 256;         // 1024 float4 chunks
    int row = c >> 4, c4 = (c & 15) * 4;
    float4 v = *(const float4*)(src + (size_t)(tr + row) * 256 + tc + c4);
    sh[row][c4] = v.x; sh[row][c4 + 1] = v.y; sh[row][c4 + 2] = v.z; sh[row][c4 + 3] = v.w;
  }
  __syncthreads();
#pragma unroll
  for (int i = 0; i < 2; i++) {
    int c = t + i * 256;         // 512 chunks of 8 bf16
    int n = c >> 3, kc = (c & 7) * 8;
    unsigned short e[8];
#pragma unroll
    for (int j = 0; j < 8; j++) e[j] = f2bf(sh[kc + j][n]);
    uint4 o;
    o.x = e[0] | ((unsigned)e[1] << 16);
    o.y = e[2] | ((unsigned)e[3] << 16);
    o.z = e[4] | ((unsigned)e[5] << 16);
    o.w = e[6] | ((unsigned)e[7] << 16);
    *(uint4*)(Wt + (size_t)mat * 65536 + (size_t)(tc + n) * 256 + tr + kc) = o;
  }
}

// ---------------- CSR build (both sides per launch) ----------------
__global__ void k_degree2(const int* __restrict__ e1, const int* __restrict__ e2,
                          int* __restrict__ cnt) {
  int b = blockIdx.x;                 // 4096
  int side = b >> 11;
  int e = (b & 2047) * 256 + threadIdx.x;
  const int* dst = (side ? e2 : e1) + NEDGE;
  atomicAdd(&cnt[side * NNODE + dst[e]], 1);
}

__global__ void k_scan2(const int* __restrict__ cnt, int* __restrict__ off,
                        int* __restrict__ cur) {
  __shared__ int sh[1024];
  int side = blockIdx.x;              // grid 2
  const int* c = cnt + side * NNODE;
  int* of = off + side * (NNODE + 64);
  int* cu = cur + side * NNODE;
  int t = threadIdx.x;
  int base = t * 32;
  int loc[32];
  int s = 0;
#pragma unroll
  for (int j = 0; j < 32; j++) { loc[j] = c[base + j]; s += loc[j]; }
  sh[t] = s;
  __syncthreads();
  for (int d = 1; d < 1024; d <<= 1) {
    int v = (t >= d) ? sh[t - d] : 0;
    __syncthreads();
    sh[t] += v;
    __syncthreads();
  }
  int run = sh[t] - s;
#pragma unroll
  for (int j = 0; j < 32; j++) { of[base + j] = run; cu[base + j] = run; run += loc[j]; }
  if (t == 1023) of[NNODE] = run;
}

__global__ void k_scatter2(const int* __restrict__ e1, const int* __restrict__ e2,
                           int* __restrict__ cur, int* __restrict__ srcs) {
  int b = blockIdx.x;                 // 4096
  int side = b >> 11;
  int e = (b & 2047) * 256 + threadIdx.x;
  const int* ei = (side ? e2 : e1);
  int d = ei[NEDGE + e];
  int p = atomicAdd(&cur[side * NNODE + d], 1);
  srcs[side * NEDGE + p] = ei[e];
}

// ---------------- fused layer: gather(+BN) -> GEMM1(relu) -> GEMM2 + stats ----------------
// grid 1024 (2 sides x 512 row-blocks of 64), 512 thr = 8 waves (2m x 4n).
// LDS 68KB: sA/sA2 [64][512B] at [0,32K), sW [256][128B] at [32K,64K), red 4K at [64K,68K).
template <bool BN>
__global__ __launch_bounds__(512, 4) void k_layer(
    const unsigned short* __restrict__ x,      // [2N][256] prev features
    const int* __restrict__ off, const int* __restrict__ srcs,
    const float* __restrict__ pstats,          // [2][2][256] prev layer (BN only)
    const float* __restrict__ pgamma, const float* __restrict__ pbeta,
    const unsigned short* __restrict__ w1t,    // [256][256] bf16 transposed
    const unsigned short* __restrict__ w2t,
    const float* __restrict__ b1, const float* __restrict__ b2,
    float* __restrict__ stats,                 // [2][2][256] this layer
    unsigned short* __restrict__ hout) {
  __shared__ __align__(16) char smem[69632];
  char* sA = smem;                 // [64][512B] swizzled bf16 (gather out / phase1 A / phase2 A)
  char* sA2 = smem;                // alias
  char* sW = smem + 32768;         // [256][128B] swizzled W chunk; later h bounce
  float2* red = (float2*)(smem + 65536);
  int tid = threadIdx.x;
  int lane = tid & 63, wid = tid >> 6;
  int wm = wid & 1, wn = wid >> 1;
  int q = lane >> 4, r = lane & 15;
  const int sw = (r & 7) << 4;
  int b = blockIdx.x;
  int side = b >> 9;
  size_t grow0 = (size_t)side * NNODE + (size_t)(b & 511) * 64;

  // ============ gather phase: aggregate 64 rows into sA ============
  {
    int hw = tid >> 5, sub = tid & 31;       // half-wave per node, 4 nodes each
    float sc[8], shf[8];
    if (BN) {
      int c0 = sub * 8;
      const float* cs = pstats + side * 512;
      const float invn = 1.f / 32768.f;
#pragma unroll
      for (int j = 0; j < 8; j++) {
        float mu = cs[c0 + j] * invn;
        float var = cs[256 + c0 + j] * invn - mu * mu;
        float s = pgamma[c0 + j] * rsqrtf(var + 1e-5f);
        sc[j] = s; shf[j] = pbeta[c0 + j] - mu * s;
      }
    }
    const uint4* X = (const uint4*)x;        // 32 uint4 per row
    size_t rbase = (size_t)side * NNODE;
    const int* offs = off + side * (NNODE + 64);
    const int* sr = srcs + (size_t)side * NEDGE;
#pragma unroll 1
    for (int nn = 0; nn < 4; nn++) {
      int lrow = hw * 4 + nn;
      int n = (int)(b & 511) * 64 + lrow;
      float a[8];
#pragma unroll
      for (int j = 0; j < 8; j++) a[j] = 0.f;
      auto acc8 = [&](uint4 u, float w) {
        unsigned uu[4] = {u.x, u.y, u.z, u.w};
#pragma unroll
        for (int j = 0; j < 4; j++) {
          float lo = __uint_as_float(uu[j] << 16);
          float hi = __uint_as_float(uu[j] & 0xFFFF0000u);
          if (BN) {
            lo = fmaxf(fmaf(lo, sc[2 * j], shf[2 * j]), 0.f);
            hi = fmaxf(fmaf(hi, sc[2 * j + 1], shf[2 * j + 1]), 0.f);
          }
          a[2 * j] = fmaf(lo, w, a[2 * j]);
          a[2 * j + 1] = fmaf(hi, w, a[2 * j + 1]);
        }
      };
      acc8(X[(rbase + n) * 32 + sub], 2.f);
      int e = offs[n], ee = offs[n + 1];
      for (; e + 3 < ee; e += 4) {
        int i0 = sr[e], i1 = sr[e + 1], i2 = sr[e + 2], i3 = sr[e + 3];
        uint4 u0 = X[(rbase + i0) * 32 + sub];
        uint4 u1 = X[(rbase + i1) * 32 + sub];
        uint4 u2 = X[(rbase + i2) * 32 + sub];
        uint4 u3 = X[(rbase + i3) * 32 + sub];
        acc8(u0, 1.f); acc8(u1, 1.f); acc8(u2, 1.f); acc8(u3, 1.f);
      }
      for (; e < ee; e++) acc8(X[(rbase + sr[e]) * 32 + sub], 1.f);
      uint4 o;
      o.x = packbf(a[0], a[1]); o.y = packbf(a[2], a[3]);
      o.z = packbf(a[4], a[5]); o.w = packbf(a[6], a[7]);
      *(uint4*)(sA + lrow * 512 + ((sub * 16) ^ ((lrow & 7) << 4))) = o;
    }
  }

  auto stageW = [&](const unsigned short* wsrc, int k0) {
    for (int c = tid; c < 2048; c += 512) {
      int row = c >> 3, cb = (c & 7) * 16;
      float4 v = *(const float4*)(wsrc + (size_t)row * 256 + k0 + (c & 7) * 8);
      *(float4*)(sW + row * 128 + (cb ^ ((row & 7) << 4))) = v;
    }
  };

  f32x4 acc[2][4];
#pragma unroll
  for (int mi = 0; mi < 2; mi++)
#pragma unroll
    for (int ni = 0; ni < 4; ni++) acc[mi][ni] = (f32x4){0.f, 0.f, 0.f, 0.f};

  stageW(w1t, 0);
  __syncthreads();

  // ---- phase 1: C1 = A @ W1 ----
  for (int k0 = 0; k0 < 256; k0 += 64) {
#pragma unroll
    for (int ks = 0; ks < 2; ks++) {
      bf16x8 af[2], bfr[4];
      int cbA = (k0 * 2 + ks * 64 + q * 16) ^ sw;
      int cbW = (ks * 64 + q * 16) ^ sw;
#pragma unroll
      for (int mi = 0; mi < 2; mi++)
        af[mi] = *(const bf16x8*)(sA + (wm * 32 + mi * 16 + r) * 512 + cbA);
#pragma unroll
      for (int ni = 0; ni < 4; ni++)
        bfr[ni] = *(const bf16x8*)(sW + (wn * 64 + ni * 16 + r) * 128 + cbW);
#pragma unroll
      for (int mi = 0; mi < 2; mi++)
#pragma unroll
        for (int ni = 0; ni < 4; ni++)
          acc[mi][ni] = __builtin_amdgcn_mfma_f32_16x16x32_bf16(af[mi], bfr[ni], acc[mi][ni], 0, 0, 0);
    }
    __syncthreads();
    if (k0 < 192) {
      stageW(w1t, k0 + 64);
      __syncthreads();
    }
  }

  // epilogue 1: bias + relu -> bf16 into sA2 (alias of sA; all reads done)
  float b1v[4];
#pragma unroll
  for (int ni = 0; ni < 4; ni++) b1v[ni] = b1[wn * 64 + ni * 16 + r];
#pragma unroll
  for (int mi = 0; mi < 2; mi++)
#pragma unroll
    for (int ni = 0; ni < 4; ni++)
#pragma unroll
      for (int j = 0; j < 4; j++) {
        float o = fmaxf(acc[mi][ni][j] + b1v[ni], 0.f);
        int rowc = wm * 32 + mi * 16 + q * 4 + j;
        int colc = wn * 64 + ni * 16 + r;
        *(unsigned short*)(sA2 + rowc * 512 + ((colc * 2) ^ (((q * 4 + j) & 7) << 4))) = f2bf(o);
      }
#pragma unroll
  for (int mi = 0; mi < 2; mi++)
#pragma unroll
    for (int ni = 0; ni < 4; ni++) acc[mi][ni] = (f32x4){0.f, 0.f, 0.f, 0.f};
  stageW(w2t, 0);
  __syncthreads();

  // ---- phase 2: C2 = relu(C1) @ W2 ----
  for (int k0 = 0; k0 < 256; k0 += 64) {
#pragma unroll
    for (int ks = 0; ks < 2; ks++) {
      bf16x8 af[2], bfr[4];
      int cbA = (k0 * 2 + ks * 64 + q * 16) ^ sw;
      int cbW = (ks * 64 + q * 16) ^ sw;
#pragma unroll
      for (int mi = 0; mi < 2; mi++)
        af[mi] = *(const bf16x8*)(sA2 + (wm * 32 + mi * 16 + r) * 512 + cbA);
#pragma unroll
      for (int ni = 0; ni < 4; ni++)
        bfr[ni] = *(const bf16x8*)(sW + (wn * 64 + ni * 16 + r) * 128 + cbW);
#pragma unroll
      for (int mi = 0; mi < 2; mi++)
#pragma unroll
        for (int ni = 0; ni < 4; ni++)
          acc[mi][ni] = __builtin_amdgcn_mfma_f32_16x16x32_bf16(af[mi], bfr[ni], acc[mi][ni], 0, 0, 0);
    }
    __syncthreads();
    if (k0 < 192) {
      stageW(w2t, k0 + 64);
      __syncthreads();
    }
  }

  // epilogue 2: bias, BN stats, bf16 out via sW bounce (sW dead after phase 2)
  float b2v[4];
#pragma unroll
  for (int ni = 0; ni < 4; ni++) b2v[ni] = b2[wn * 64 + ni * 16 + r];
#pragma unroll
  for (int ni = 0; ni < 4; ni++) {
    float ss = 0.f, sq = 0.f;
#pragma unroll
    for (int mi = 0; mi < 2; mi++)
#pragma unroll
      for (int j = 0; j < 4; j++) {
        float o = acc[mi][ni][j] + b2v[ni];
        acc[mi][ni][j] = o;
        ss += o; sq += o * o;
      }
    ss += __shfl_xor(ss, 16, 64); ss += __shfl_xor(ss, 32, 64);
    sq += __shfl_xor(sq, 16, 64); sq += __shfl_xor(sq, 32, 64);
    if (q == 0) {
      float2 w; w.x = ss; w.y = sq;
      red[(wn * 64 + ni * 16 + r) * 2 + wm] = w;
    }
  }
#pragma unroll
  for (int mi = 0; mi < 2; mi++)
#pragma unroll
    for (int ni = 0; ni < 4; ni++)
#pragma unroll
      for (int j = 0; j < 4; j++) {
        int rowc = wm * 32 + mi * 16 + q * 4 + j;
        int colc = wn * 64 + ni * 16 + r;
        *(unsigned short*)(sW + rowc * 512 + ((colc * 2) ^ (((q * 4 + j) & 7) << 4))) =
            f2bf(acc[mi][ni][j]);
      }
  __syncthreads();
  float* cs = stats + side * 512;
  if (tid < 256) {
    float2 a = red[tid * 2], c2 = red[tid * 2 + 1];
    atomicAdd(&cs[tid], a.x + c2.x);
    atomicAdd(&cs[256 + tid], a.y + c2.y);
  }
  for (int c = tid; c < 2048; c += 512) {   // 64 rows x 32 chunks of 16B
    int row = c >> 5, cb = (c & 31) * 16;
    float4 v = *(const float4*)(sW + row * 512 + (cb ^ ((row & 7) << 4)));
    *(float4*)(hout + (grow0 + row) * 256 + (c & 31) * 8) = v;
  }
}

// ---------------- per-graph sum of relu(bn(h)) ----------------
__global__ __launch_bounds__(256) void k_gsum(
    const unsigned short* __restrict__ h, const float* __restrict__ stats,
    const float* __restrict__ gamma, const float* __restrict__ beta,
    float* __restrict__ sg) {
  int b = blockIdx.x;            // 256 = 2 sides x 128 graphs
  int side = b >> 7, g = b & 127;
  int t = threadIdx.x;
  int c0 = (t & 63) * 4, rg = t >> 6;
  const float* cs = stats + side * 512;
  float sc[4], sh_[4];
#pragma unroll
  for (int j = 0; j < 4; j++) {
    float mu = cs[c0 + j] * (1.f / 32768.f);
    float var = cs[256 + c0 + j] * (1.f / 32768.f) - mu * mu;
    float s = gamma[c0 + j] * rsqrtf(var + 1e-5f);
    sc[j] = s; sh_[j] = beta[c0 + j] - mu * s;
  }
  size_t base = (size_t)side * NNODE + (size_t)g * 256;
  float acc = 0.f;
  for (int k = 0; k < 64; k++) {
    int row = rg + k * 4;
    ushort4 u = *(const ushort4*)(h + (base + row) * 256 + c0);
    acc += fmaxf(fmaf(bf2f(u.x), sc[0], sh_[0]), 0.f);
    acc += fmaxf(fmaf(bf2f(u.y), sc[1], sh_[1]), 0.f);
    acc += fmaxf(fmaf(bf2f(u.z), sc[2], sh_[2]), 0.f);
    acc += fmaxf(fmaf(bf2f(u.w), sc[3], sh_[3]), 0.f);
  }
  __shared__ float red[256];
  red[t] = acc;
  __syncthreads();
  if (t < 64) {
    float s = red[t] + red[t + 64] + red[t + 128] + red[t + 192];
#pragma unroll
    for (int m = 1; m < 64; m <<= 1) s += __shfl_xor(s, m, 64);
    if (t == 0) sg[b] = s;
  }
}

// ---------------- final: p = sg1 - sg2, min-max normalize, exp(-p) ----------------
__global__ void k_final(const float* __restrict__ sg1, const float* __restrict__ sg2,
                        float* __restrict__ out) {
  int t = threadIdx.x;   // 64 threads
  float a = sg1[t] - sg2[t];
  float b = sg1[t + 64] - sg2[t + 64];
  float mn = fminf(a, b), mx = fmaxf(a, b);
#pragma unroll
  for (int msk = 1; msk < 64; msk <<= 1) {
    mn = fminf(mn, __shfl_xor(mn, msk, 64));
    mx = fmaxf(mx, __shfl_xor(mx, msk, 64));
  }
  float inv = 1.0f / (mx - mn);
  out[t] = __expf(-(a - mn) * inv);
  out[t + 64] = __expf(-(b - mn) * inv);
}

// ---------------- host ----------------
extern "C" void kernel_launch(void* const* d_in, const int* in_sizes, int n_in,
                              void* d_out, int out_size, void* d_ws, size_t ws_size,
                              hipStream_t stream) {
  (void)in_sizes; (void)n_in; (void)out_size; (void)ws_size;
  const float* f1 = (const float*)d_in[0];
  const float* f2 = (const float*)d_in[1];
  const int* e1 = (const int*)d_in[2];
  const int* e2 = (const int*)d_in[3];
  const float* gw1 = (const float*)d_in[5];
  const float* gb1 = (const float*)d_in[6];
  const float* gw2 = (const float*)d_in[7];
  const float* gb2 = (const float*)d_in[8];
  const float* gga = (const float*)d_in[9];
  const float* gbe = (const float*)d_in[10];
  float* out = (float*)d_out;

  char* ws = (char*)d_ws;
  size_t o = 0;
  auto alloc = [&](size_t bytes) { void* p = ws + o; o += (bytes + 255) & ~(size_t)255; return p; };
  unsigned short* hb0 = (unsigned short*)alloc(2ull * NNODE * 256 * 2);
  unsigned short* hb1 = (unsigned short*)alloc(2ull * NNODE * 256 * 2);
  unsigned short* Wt = (unsigned short*)alloc(6ull * 65536 * 2);
  float* stats = (float*)alloc(3 * 1024 * 4);      // [layer][side][{sum,sq}][256]
  float* sg = (float*)alloc(256 * 4);
  int* cnt = (int*)alloc(2 * NNODE * 4);
  int* off = (int*)alloc(2 * (NNODE + 64) * 4);
  int* cur = (int*)alloc(2 * NNODE * 4);
  int* srcs = (int*)alloc(2ull * NEDGE * 4);

  (void)hipMemsetAsync(stats, 0, 3 * 1024 * 4, stream);
  (void)hipMemsetAsync(cnt, 0, 2 * NNODE * 4, stream);

  k_conv<<<16384, 256, 0, stream>>>(f1, f2, hb0);
  k_wprep<<<96, 256, 0, stream>>>(gw1, gw2, Wt);
  k_degree2<<<4096, 256, 0, stream>>>(e1, e2, cnt);
  k_scan2<<<2, 1024, 0, stream>>>(cnt, off, cur);
  k_scatter2<<<4096, 256, 0, stream>>>(e1, e2, cur, srcs);

  unsigned short* hb[2] = {hb0, hb1};
  for (int l = 0; l < 3; l++) {
    unsigned short* xin = hb[l & 1];
    unsigned short* hout = hb[1 - (l & 1)];
    if (l == 0)
      k_layer<false><<<1024, 512, 0, stream>>>(
          xin, off, srcs, nullptr, nullptr, nullptr,
          Wt + (size_t)l * 65536, Wt + (size_t)(3 + l) * 65536,
          gb1 + l * 256, gb2 + l * 256, stats + l * 1024, hout);
    else
      k_layer<true><<<1024, 512, 0, stream>>>(
          xin, off, srcs, stats + (l - 1) * 1024, gga + (l - 1) * 256, gbe + (l - 1) * 256,
          Wt + (size_t)l * 65536, Wt + (size_t)(3 + l) * 65536,
          gb1 + l * 256, gb2 + l * 256, stats + l * 1024, hout);
  }

  k_gsum<<<256, 256, 0, stream>>>(hb1, stats + 2 * 1024, gga + 512, gbe + 512, sg);
  k_final<<<1, 64, 0, stream>>>(sg, sg + 128, out);
}